// Round 12
// baseline (2388.665 us; speedup 1.0000x reference)
//
#include <hip/hip_runtime.h>
#include <hip/hip_bf16.h>
#include <math.h>

typedef __attribute__((ext_vector_type(8))) short bf16x8;
typedef __attribute__((ext_vector_type(4))) float f32x4;

static constexpr int Bv   = 2;
static constexpr int Tv   = 1024;
static constexpr int Cv   = 768;
static constexpr int Hv   = 12;
static constexpr int Lv   = 4;
static constexpr int Vv   = 50257;
static constexpr int Mv   = 2048;
static constexpr int NT2  = 197;          // lm-head col tiles of 256
static constexpr float EPSv = 1e-6f;

// ---------------------------------------------------------------------------
__device__ __forceinline__ void gload16(const void* g, void* l) {
    __builtin_amdgcn_global_load_lds((const __attribute__((address_space(1))) void*)g,
                                     (__attribute__((address_space(3))) void*)l, 16, 0, 0);
}
template<int N>
__device__ __forceinline__ void waitvm_barrier() {
    if constexpr (N == 0)      asm volatile("s_waitcnt vmcnt(0)\ns_barrier" ::: "memory");
    else if constexpr (N == 2) asm volatile("s_waitcnt vmcnt(2)\ns_barrier" ::: "memory");
    else if constexpr (N == 3) asm volatile("s_waitcnt vmcnt(3)\ns_barrier" ::: "memory");
    else if constexpr (N == 4) asm volatile("s_waitcnt vmcnt(4)\ns_barrier" ::: "memory");
    else if constexpr (N == 6) asm volatile("s_waitcnt vmcnt(6)\ns_barrier" ::: "memory");
    else                       asm volatile("s_waitcnt vmcnt(8)\ns_barrier" ::: "memory");
}
__device__ __forceinline__ void lgkm0_barrier() {
    asm volatile("s_waitcnt lgkmcnt(0)\ns_barrier" ::: "memory");
}

// ---------------------------------------------------------------------------
__global__ void embed_kernel(const int* __restrict__ idx,
                             const float* __restrict__ wte,
                             const float* __restrict__ wpe,
                             float* __restrict__ x) {
    int row = blockIdx.x;
    int t   = row & (Tv - 1);
    int tok = idx[row];
    const float* src = wte + (size_t)tok * Cv;
    const float* pos = wpe + (size_t)t * Cv;
    float* dst = x + (size_t)row * Cv;
    for (int c = threadIdx.x; c < Cv; c += 256)
        dst[c] = src[c] + pos[c];
}

// ---------------------------------------------------------------------------
__device__ __forceinline__ ushort4 pack4bf(float4 v) {
    ushort4 u;
    u.x = __bfloat16_as_ushort(__float2bfloat16(v.x));
    u.y = __bfloat16_as_ushort(__float2bfloat16(v.y));
    u.z = __bfloat16_as_ushort(__float2bfloat16(v.z));
    u.w = __bfloat16_as_ushort(__float2bfloat16(v.w));
    return u;
}

// LayerNorm, one wave per row. fp32 in -> bf16 out. grid 512 x 256.
__global__ void ln_kernel(const float* __restrict__ in,
                          const float* __restrict__ sc,
                          const float* __restrict__ bi,
                          __hip_bfloat16* __restrict__ out) {
    int row  = blockIdx.x * 4 + (threadIdx.x >> 6);
    int lane = threadIdx.x & 63;
    const float4* xr = (const float4*)(in + (size_t)row * Cv);
    float4 a = xr[lane], b = xr[lane + 64], c = xr[lane + 128];
    float sum = a.x + a.y + a.z + a.w + b.x + b.y + b.z + b.w + c.x + c.y + c.z + c.w;
    float sq  = a.x*a.x + a.y*a.y + a.z*a.z + a.w*a.w
              + b.x*b.x + b.y*b.y + b.z*b.z + b.w*b.w
              + c.x*c.x + c.y*c.y + c.z*c.z + c.w*c.w;
    #pragma unroll
    for (int off = 32; off; off >>= 1) {
        sum += __shfl_xor(sum, off, 64);
        sq  += __shfl_xor(sq,  off, 64);
    }
    float mean = sum * (1.0f / Cv);
    float var  = sq * (1.0f / Cv) - mean * mean;
    float rs   = rsqrtf(var + EPSv);
    const float4* s4 = (const float4*)sc;
    const float4* b4 = (const float4*)bi;
    ushort4* orow = (ushort4*)(out + (size_t)row * Cv);
    #pragma unroll
    for (int i = 0; i < 3; ++i) {
        float4 v = (i == 0) ? a : (i == 1) ? b : c;
        float4 s = s4[lane + 64 * i];
        float4 t = b4[lane + 64 * i];
        float4 o;
        o.x = (v.x - mean) * rs * s.x + t.x;
        o.y = (v.y - mean) * rs * s.y + t.y;
        o.z = (v.z - mean) * rs * s.z + t.z;
        o.w = (v.w - mean) * rs * s.w + t.w;
        orow[lane + 64 * i] = pack4bf(o);
    }
}

// ---------------------------------------------------------------------------
// ALL weight transposes + wte cvt + lossSlot zero in ONE launch.
// blocks: [0,6912) attn, [6912,9216) aproj, [9216,18432) fc,
//         [18432,27648) mproj, [27648, 32384) wte fp32->bf16 grid-stride
// ---------------------------------------------------------------------------
__global__ void wtrans_all_kernel(const float* __restrict__ a0, __hip_bfloat16* __restrict__ o0,
                                  const float* __restrict__ a1, __hip_bfloat16* __restrict__ o1,
                                  const float* __restrict__ a2, __hip_bfloat16* __restrict__ o2,
                                  const float* __restrict__ a3, __hip_bfloat16* __restrict__ o3,
                                  const float* __restrict__ wte, __hip_bfloat16* __restrict__ wte_bf,
                                  float* __restrict__ lossSlot) {
    int bid = blockIdx.x;
    if (bid >= 27648) {                    // wte convert part
        int cb = bid - 27648;
        if (cb == 0 && threadIdx.x == 0) *lossSlot = 0.f;
        int n4 = (Vv * Cv) / 4;
        int stride = 4736 * 256;
        for (int i = cb * 256 + threadIdx.x; i < n4; i += stride) {
            float4 v = ((const float4*)wte)[i];
            ((ushort4*)wte_bf)[i] = pack4bf(v);
        }
        return;
    }
    __shared__ float tile[32][33];
    const float* in; __hip_bfloat16* out; int K, N, t;
    if (bid < 6912)       { int l = bid / 1728;          t = bid % 1728;
        in = a0 + (size_t)l * 768 * 2304; out = o0 + (size_t)l * 2304 * 768; K = 768;  N = 2304; }
    else if (bid < 9216)  { int r = bid - 6912;  int l = r / 576;  t = r % 576;
        in = a1 + (size_t)l * 768 * 768;  out = o1 + (size_t)l * 768 * 768;  K = 768;  N = 768;  }
    else if (bid < 18432) { int r = bid - 9216;  int l = r / 2304; t = r % 2304;
        in = a2 + (size_t)l * 768 * 3072; out = o2 + (size_t)l * 3072 * 768; K = 768;  N = 3072; }
    else                  { int r = bid - 18432; int l = r / 2304; t = r % 2304;
        in = a3 + (size_t)l * 3072 * 768; out = o3 + (size_t)l * 768 * 3072; K = 3072; N = 768;  }
    int nx = N / 32;
    int n0 = (t % nx) * 32, k0 = (t / nx) * 32;
    int tx = threadIdx.x & 31, ty = threadIdx.x >> 5;
    #pragma unroll
    for (int i = 0; i < 4; ++i)
        tile[ty + i * 8][tx] = in[(size_t)(k0 + ty + i * 8) * N + n0 + tx];
    __syncthreads();
    #pragma unroll
    for (int i = 0; i < 4; ++i)
        out[(size_t)(n0 + ty + i * 8) * K + k0 + tx] =
            __float2bfloat16(tile[tx][ty + i * 8]);
}

// ---------------------------------------------------------------------------
// Loop GEMM, BK=64, 2-buffer 2-phase schedule (unchanged from round 11).
// ---------------------------------------------------------------------------
template<int EPI, int BM>
__launch_bounds__(256)
__global__ void gemm_bf16(const __hip_bfloat16* __restrict__ A,
                          const __hip_bfloat16* __restrict__ Bt,
                          const float* __restrict__ bias,
                          const float* R, float* Cf,
                          __hip_bfloat16* __restrict__ Cb,
                          __hip_bfloat16* __restrict__ vt,
                          int M, int N, int K) {
    constexpr int FM  = BM / 32;
    constexpr int NIA = BM / 32;
    constexpr int LPT = NIA + 2;
    __shared__ __hip_bfloat16 As[2][BM * 64];
    __shared__ __hip_bfloat16 Bs[2][64 * 64];
    int tid = threadIdx.x;
    int wave = tid >> 6, lane = tid & 63;
    int wr = wave >> 1, wc = wave & 1;
    int rowBase = blockIdx.y * BM, colBase = blockIdx.x * 64;

    f32x4 acc[FM][2] = {};

    int r8 = lane >> 3;
    int cg = ((lane & 7) ^ r8) * 8;
    const __hip_bfloat16* ApS = A  + (size_t)(rowBase + wave * 8 + r8) * K + cg;
    const __hip_bfloat16* BpS = Bt + (size_t)(colBase + wave * 8 + r8) * K + cg;

    auto stage = [&](int buf, int t) {
        int k0 = t * 64;
        #pragma unroll
        for (int i = 0; i < NIA; ++i)
            gload16(ApS + (size_t)(i * 32) * K + k0, &As[buf][(i * 32 + wave * 8) * 64]);
        #pragma unroll
        for (int i = 0; i < 2; ++i)
            gload16(BpS + (size_t)(i * 32) * K + k0, &Bs[buf][(i * 32 + wave * 8) * 64]);
    };

    int fq = lane >> 4, fr = lane & 15;
    int fr7 = fr & 7;

    int nt = K / 64;
    stage(0, 0); stage(1, 1);
    waitvm_barrier<LPT>();

    for (int t = 0; t < nt; ++t) {
        int cur = t & 1;
        const __hip_bfloat16* Ab = &As[cur][0];
        const __hip_bfloat16* Bb = &Bs[cur][0];

        bf16x8 av0[FM], bv0[2];
        #pragma unroll
        for (int m = 0; m < FM; ++m)
            av0[m] = *(const bf16x8*)&Ab[(wr * (BM / 2) + m * 16 + fr) * 64 + ((fq ^ fr7) * 8)];
        #pragma unroll
        for (int n = 0; n < 2; ++n)
            bv0[n] = *(const bf16x8*)&Bb[(wc * 32 + n * 16 + fr) * 64 + ((fq ^ fr7) * 8)];
        __builtin_amdgcn_s_setprio(1);
        #pragma unroll
        for (int m = 0; m < FM; ++m)
            #pragma unroll
            for (int n = 0; n < 2; ++n)
                acc[m][n] = __builtin_amdgcn_mfma_f32_16x16x32_bf16(
                    av0[m], bv0[n], acc[m][n], 0, 0, 0);
        __builtin_amdgcn_s_setprio(0);

        bf16x8 av1[FM], bv1[2];
        #pragma unroll
        for (int m = 0; m < FM; ++m)
            av1[m] = *(const bf16x8*)&Ab[(wr * (BM / 2) + m * 16 + fr) * 64 + (((4 + fq) ^ fr7) * 8)];
        #pragma unroll
        for (int n = 0; n < 2; ++n)
            bv1[n] = *(const bf16x8*)&Bb[(wc * 32 + n * 16 + fr) * 64 + (((4 + fq) ^ fr7) * 8)];
        lgkm0_barrier();

        if (t + 2 < nt) stage(cur, t + 2);

        __builtin_amdgcn_s_setprio(1);
        #pragma unroll
        for (int m = 0; m < FM; ++m)
            #pragma unroll
            for (int n = 0; n < 2; ++n)
                acc[m][n] = __builtin_amdgcn_mfma_f32_16x16x32_bf16(
                    av1[m], bv1[n], acc[m][n], 0, 0, 0);
        __builtin_amdgcn_s_setprio(0);

        if (t + 2 < nt) waitvm_barrier<LPT>();
        else            waitvm_barrier<0>();
    }

    // Fused V-transpose path (qkv GEMM only).
    if (EPI == 0 && vt != nullptr && (blockIdx.x % 3) == 2) {
        __hip_bfloat16 (*Ts)[132] = (__hip_bfloat16(*)[132])&As[0][0];
        #pragma unroll
        for (int m = 0; m < FM; ++m) {
            #pragma unroll
            for (int n = 0; n < 2; ++n) {
                int dloc = wc * 32 + n * 16 + fr;
                #pragma unroll
                for (int j = 0; j < 4; ++j) {
                    int tl = wr * (BM / 2) + m * 16 + fq * 4 + j;
                    float val = acc[m][n][j] + bias[colBase + dloc];
                    Ts[dloc][tl] = __float2bfloat16(val);
                }
            }
        }
        __syncthreads();
        int h  = blockIdx.x / 3;
        int b  = rowBase >> 10;
        int bh = b * Hv + h;
        int t0 = rowBase & 1023;
        int d = tid >> 2, part = tid & 3;
        const ushort4* src = (const ushort4*)&Ts[d][part * 32];
        ushort4* dst = (ushort4*)((__hip_bfloat16*)vt +
                       ((size_t)bh * 64 + d) * Tv + t0 + part * 32);
        #pragma unroll
        for (int i = 0; i < 8; ++i) dst[i] = src[i];
        return;
    }

    #pragma unroll
    for (int m = 0; m < FM; ++m) {
        #pragma unroll
        for (int n = 0; n < 2; ++n) {
            f32x4 v = acc[m][n];
            int col = colBase + wc * 32 + n * 16 + fr;
            #pragma unroll
            for (int j = 0; j < 4; ++j) {
                int row = rowBase + wr * (BM / 2) + m * 16 + fq * 4 + j;
                float val = v[j] + bias[col];
                if (EPI == 1) {
                    val += R[(size_t)row * N + col];
                    Cf[(size_t)row * N + col] = val;
                } else {
                    if (EPI == 2) {
                        float u = val;
                        float cc = 0.7978845608028654f * (u + 0.044715f * u * u * u);
                        val = 0.5f * u * (1.0f + tanhf(cc));
                    }
                    Cb[(size_t)row * N + col] = __float2bfloat16(val);
                }
            }
        }
    }
}

// ---------------------------------------------------------------------------
// MFMA flash attention (unchanged).
// ---------------------------------------------------------------------------
__launch_bounds__(256)
__global__ void attn_kernel(const __hip_bfloat16* __restrict__ qkv,
                            const __hip_bfloat16* __restrict__ vt,
                            __hip_bfloat16* __restrict__ att) {
    __shared__ __hip_bfloat16 Qs[64 * 64];
    __shared__ __hip_bfloat16 Ks[64 * 64];
    __shared__ __hip_bfloat16 Vs[64 * 64];   // Vs[d][k]
    __shared__ __hip_bfloat16 Ps[64 * 64];
    int bh = blockIdx.x;
    int b = bh / Hv, h = bh % Hv;
    int qt = (int)gridDim.y - 1 - (int)blockIdx.y;
    int q0 = qt * 64;
    int tid = threadIdx.x, wave = tid >> 6, lane = tid & 63;
    int g = lane >> 4, fr = lane & 15;
    int srow8 = lane >> 3, sc8 = lane & 7;

    const __hip_bfloat16* qbase = qkv + (size_t)(b * Tv + q0) * 2304 + h * 192;
    #pragma unroll
    for (int i = 0; i < 2; ++i) {
        int row = wave * 16 + i * 8 + srow8;
        gload16(qbase + (size_t)row * 2304 + ((sc8 ^ (row & 7)) * 8),
                Qs + (wave * 16 + i * 8) * 64);
    }

    f32x4 accO[4] = {};
    float mrun[4] = {-1e30f, -1e30f, -1e30f, -1e30f};
    float lrun[4] = {0.f, 0.f, 0.f, 0.f};

    for (int kv = 0; kv <= qt; ++kv) {
        int s0 = kv * 64;
        __syncthreads();
        const __hip_bfloat16* kbase = qkv + (size_t)(b * Tv + s0) * 2304 + h * 192 + 64;
        const __hip_bfloat16* vbase = vt + (size_t)bh * 64 * Tv + s0;
        #pragma unroll
        for (int i = 0; i < 2; ++i) {
            int row = wave * 16 + i * 8 + srow8;
            gload16(kbase + (size_t)row * 2304 + ((sc8 ^ (row & 7)) * 8),
                    Ks + (wave * 16 + i * 8) * 64);
            gload16(vbase + (size_t)row * Tv + ((sc8 ^ (row & 7)) * 8),
                    Vs + (wave * 16 + i * 8) * 64);
        }
        __syncthreads();

        f32x4 s4[4] = {};
        #pragma unroll
        for (int kk = 0; kk < 2; ++kk) {
            int qrow = wave * 16 + fr;
            bf16x8 qa = *(const bf16x8*)&Qs[qrow * 64 + (((g + 4 * kk) ^ (fr & 7)) * 8)];
            #pragma unroll
            for (int n = 0; n < 4; ++n) {
                int krow = n * 16 + fr;
                bf16x8 kb = *(const bf16x8*)&Ks[krow * 64 + (((g + 4 * kk) ^ (fr & 7)) * 8)];
                s4[n] = __builtin_amdgcn_mfma_f32_16x16x32_bf16(qa, kb, s4[n], 0, 0, 0);
            }
        }

        bool dia = (kv == qt);
        #pragma unroll
        for (int j = 0; j < 4; ++j) {
            int qg = q0 + wave * 16 + g * 4 + j;
            float sj[4], mx = -1e30f;
            #pragma unroll
            for (int n = 0; n < 4; ++n) {
                float v = s4[n][j] * 0.125f;
                if (dia && (s0 + n * 16 + fr) > qg) v = -1e30f;
                sj[n] = v;
                mx = fmaxf(mx, v);
            }
            #pragma unroll
            for (int off = 1; off < 16; off <<= 1)
                mx = fmaxf(mx, __shfl_xor(mx, off, 64));
            float mnew = fmaxf(mrun[j], mx);
            float ps = 0.f;
            unsigned short pb[4];
            #pragma unroll
            for (int n = 0; n < 4; ++n) {
                float p = __expf(sj[n] - mnew);
                __hip_bfloat16 pc = __float2bfloat16(p);
                pb[n] = __bfloat16_as_ushort(pc);
                ps += __bfloat162float(pc);
            }
            #pragma unroll
            for (int off = 1; off < 16; off <<= 1)
                ps += __shfl_xor(ps, off, 64);
            float cr = __expf(mrun[j] - mnew);
            lrun[j] = lrun[j] * cr + ps;
            mrun[j] = mnew;
            int prow = wave * 16 + g * 4 + j;
            #pragma unroll
            for (int n = 0; n < 4; ++n) {
                int byteoff = (32 * n + 2 * fr) ^ ((prow & 7) << 4);
                ((unsigned short*)Ps)[prow * 64 + (byteoff >> 1)] = pb[n];
            }
            #pragma unroll
            for (int n = 0; n < 4; ++n) accO[n][j] *= cr;
        }
        __syncthreads();

        #pragma unroll
        for (int kk = 0; kk < 2; ++kk) {
            int prow = wave * 16 + fr;
            bf16x8 pa = *(const bf16x8*)&Ps[prow * 64 + (((g + 4 * kk) ^ (fr & 7)) * 8)];
            #pragma unroll
            for (int n = 0; n < 4; ++n) {
                int vrow = n * 16 + fr;
                bf16x8 vb = *(const bf16x8*)&Vs[vrow * 64 + (((g + 4 * kk) ^ (fr & 7)) * 8)];
                accO[n] = __builtin_amdgcn_mfma_f32_16x16x32_bf16(pa, vb, accO[n], 0, 0, 0);
            }
        }
    }

    #pragma unroll
    for (int j = 0; j < 4; ++j) {
        float inv = 1.0f / lrun[j];
        int row = b * Tv + q0 + wave * 16 + g * 4 + j;
        #pragma unroll
        for (int n = 0; n < 4; ++n)
            att[(size_t)row * Cv + h * 64 + n * 16 + fr] =
                __float2bfloat16(accO[n][j] * inv);
    }
}

// ---------------------------------------------------------------------------
// lm-head: 256x256 tile, 8 waves, BK=32, 2-buffer counted-vmcnt pipeline.
// LDS 68 KB -> 2 blocks/CU (store drain of one block overlaps the other's
// K-loop). Swizzle: slot = (fq ^ fr ^ (fr>>2)) & 3 (2-way residual = free).
// grid 1576 = 8 rowT x 197 colT, bijective XCD swizzle.
// ---------------------------------------------------------------------------
__launch_bounds__(512, 4)
__global__ void lmhead_kernel(const __hip_bfloat16* __restrict__ A,
                              const __hip_bfloat16* __restrict__ Bt,
                              float* __restrict__ Cf,
                              float* __restrict__ pLse) {
    constexpr int K = Cv, N = Vv;
    constexpr int nt = K / 32;               // 24
    __shared__ __hip_bfloat16 As[2][8192];   // [256 rows][32 k] swizzled chunks
    __shared__ __hip_bfloat16 Bs[2][8192];
    __shared__ float ps[4][256];

    int bid = blockIdx.x;
    int nid = (bid & 7) * NT2 + (bid >> 3);  // 1576 = 8*197 -> bijective
    int rowT = nid & 7, colT = nid >> 3;
    int rowBase = rowT * 256, colBase = colT * 256;

    int tid = threadIdx.x;
    int wv = tid >> 6, lane = tid & 63;
    int wr = wv >> 2, wc = wv & 3;           // 2 (M) x 4 (N) wave grid
    int fq = lane >> 4, fr = lane & 15;
    int slot0 = (fq ^ fr ^ (fr >> 2)) & 3;   // swizzled k-chunk slot

    f32x4 acc[8][4] = {};

    // staging: per wave 32 A-rows + 32 B-rows; 2 instrs each (16 rows/instr).
    // lane covers r_local = i*16 + (lane>>2), chunk lane&3; source chunk
    // pre-swizzled so that LDS slot c holds global chunk c ^ swz(row).
    int rl   = lane >> 2;                    // 0..15 row within instr group
    int swzr = (rl ^ (rl >> 2)) & 3;
    int cOff = ((lane & 3) ^ swzr) * 8;      // element offset in source row
    const __hip_bfloat16* ApS[2];
    const __hip_bfloat16* BpS[2];
    #pragma unroll
    for (int i = 0; i < 2; ++i) {
        int rit = wv * 32 + i * 16 + rl;     // row in tile 0..255
        ApS[i] = A + (size_t)(rowBase + rit) * K + cOff;
        int rb = colBase + rit;
        if (rb >= N) rb = N - 1;
        BpS[i] = Bt + (size_t)rb * K + cOff;
    }

    auto stage = [&](int buf, int tile) {
        int k0 = tile * 32;
        #pragma unroll
        for (int i = 0; i < 2; ++i)
            gload16(ApS[i] + k0, &As[buf][(wv * 32 + i * 16) * 32]);
        #pragma unroll
        for (int i = 0; i < 2; ++i)
            gload16(BpS[i] + k0, &Bs[buf][(wv * 32 + i * 16) * 32]);
    };

    stage(0, 0);
    stage(1, 1);
    waitvm_barrier<4>();                     // tile 0 resident

    for (int t = 0; t < nt; ++t) {
        int cur = t & 1;
        const __hip_bfloat16* Ab = &As[cur][0];
        const __hip_bfloat16* Bb = &Bs[cur][0];

        bf16x8 av[8], bv[4];
        #pragma unroll
        for (int m = 0; m < 8; ++m)
            av[m] = *(const bf16x8*)&Ab[(wr * 128 + m * 16 + fr) * 32 + slot0 * 8];
        #pragma unroll
        for (int n = 0; n < 4; ++n)
            bv[n] = *(const bf16x8*)&Bb[(wc * 64 + n * 16 + fr) * 32 + slot0 * 8];
        lgkm0_barrier();                     // buffer cur free

        if (t + 2 < nt) stage(cur, t + 2);   // restage freed buffer

        __builtin_amdgcn_s_setprio(1);
        #pragma unroll
        for (int m = 0; m < 8; ++m)
            #pragma unroll
            for (int n = 0; n < 4; ++n)
                acc[m][n] = __builtin_amdgcn_mfma_f32_16x16x32_bf16(
                    av[m], bv[n], acc[m][n], 0, 0, 0);
        __builtin_amdgcn_s_setprio(0);

        if (t + 2 < nt) waitvm_barrier<4>(); // tile t+1 resident; t+2 in flight
        else            waitvm_barrier<0>();
    }

    // epilogue: store logits + per-row partial exp-sum
    #pragma unroll
    for (int m = 0; m < 8; ++m) {
        #pragma unroll
        for (int j = 0; j < 4; ++j) {
            int row = rowBase + wr * 128 + m * 16 + fq * 4 + j;
            float s = 0.f;
            #pragma unroll
            for (int n = 0; n < 4; ++n) {
                int col = colBase + wc * 64 + n * 16 + fr;
                float v = acc[m][n][j];
                if (col < N) {
                    Cf[(size_t)row * N + col] = v;
                    s += __expf(v);
                }
            }
            #pragma unroll
            for (int off = 1; off < 16; off <<= 1)
                s += __shfl_xor(s, off, 64);
            if (fr == 0)
                ps[wc][wr * 128 + m * 16 + fq * 4 + j] = s;
        }
    }
    __syncthreads();
    if (tid < 256)
        pLse[(size_t)(rowBase + tid) * NT2 + colT] =
            ps[0][tid] + ps[1][tid] + ps[2][tid] + ps[3][tid];
}

// ---------------------------------------------------------------------------
__global__ void plse_reduce_kernel(const float* __restrict__ pLse,
                                   const float* __restrict__ logits,
                                   const int* __restrict__ targets,
                                   float* __restrict__ lossOut) {
    int wave = threadIdx.x >> 6;
    int row  = blockIdx.x * 4 + wave;
    int lane = threadIdx.x & 63;
    const float* pr = pLse + (size_t)row * NT2;
    float l = 0.f;
    for (int i = lane; i < NT2; i += 64) l += pr[i];
    #pragma unroll
    for (int off = 32; off; off >>= 1) l += __shfl_xor(l, off, 64);
    __shared__ float sr[4];
    if (lane == 0)
        sr[wave] = logf(l) - logits[(size_t)row * Vv + targets[row]];
    __syncthreads();
    if (threadIdx.x == 0)
        atomicAdd(lossOut, (sr[0] + sr[1] + sr[2] + sr[3]) * (1.0f / Mv));
}

// ---------------------------------------------------------------------------
extern "C" void kernel_launch(void* const* d_in, const int* in_sizes, int n_in,
                              void* d_out, int out_size, void* d_ws, size_t ws_size,
                              hipStream_t stream) {
    const int*   idx     = (const int*)  d_in[0];
    const int*   targets = (const int*)  d_in[1];
    const float* wte     = (const float*)d_in[2];
    const float* wpe     = (const float*)d_in[3];
    const float* ln1_s   = (const float*)d_in[4];
    const float* ln1_b   = (const float*)d_in[5];
    const float* attn_k  = (const float*)d_in[6];
    const float* attn_b  = (const float*)d_in[7];
    const float* aproj_k = (const float*)d_in[8];
    const float* aproj_b = (const float*)d_in[9];
    const float* ln2_s   = (const float*)d_in[10];
    const float* ln2_b   = (const float*)d_in[11];
    const float* fc_k    = (const float*)d_in[12];
    const float* fc_b    = (const float*)d_in[13];
    const float* mproj_k = (const float*)d_in[14];
    const float* mproj_b = (const float*)d_in[15];
    const float* lnf_s   = (const float*)d_in[16];
    const float* lnf_b   = (const float*)d_in[17];

    float* out = (float*)d_out;
    char* ws  = (char*)d_ws;
    char* ob  = (char*)d_out;   // d_out doubles as loop-time scratch

    constexpr size_t NEED = 81962496ULL;
    if (ws_size < NEED) return;

    // ws: live through lm-head
    __hip_bfloat16* wte_bf = (__hip_bfloat16*)(ws + 0);          // 77,194,752
    __hip_bfloat16* h_bf   = (__hip_bfloat16*)(ws + 77194752);   //  3,145,728
    float*          pLse   = (float*)(ws + 80340480);            //  1,613,824

    // d_out scratch: all dead before lmhead writes logits
    float*          x      = (float*)(ob + 0);                   //  6,291,456
    __hip_bfloat16* qkv_bf = (__hip_bfloat16*)(ob + 6291456);    //  9,437,184
    __hip_bfloat16* vt_bf  = (__hip_bfloat16*)(ob + 15728640);   //  3,145,728
    __hip_bfloat16* att_bf = (__hip_bfloat16*)(ob + 18874368);   //  3,145,728
    __hip_bfloat16* fco_bf = (__hip_bfloat16*)(ob + 22020096);   // 12,582,912
    __hip_bfloat16* w0     = (__hip_bfloat16*)(ob + 34603008);   // 14,155,776 (4 layers)
    __hip_bfloat16* w1     = (__hip_bfloat16*)(ob + 48758784);   //  4,718,592
    __hip_bfloat16* w2     = (__hip_bfloat16*)(ob + 53477376);   // 18,874,368
    __hip_bfloat16* w3     = (__hip_bfloat16*)(ob + 72351744);   // 18,874,368

    float* lossSlot = out + (out_size - 1);

    embed_kernel<<<Mv, 256, 0, stream>>>(idx, wte, wpe, x);

    // all weight transposes + wte convert + lossSlot zero in one launch
    wtrans_all_kernel<<<32384, 256, 0, stream>>>(
        attn_k, w0, aproj_k, w1, fc_k, w2, mproj_k, w3, wte, wte_bf, lossSlot);

    for (int l = 0; l < Lv; ++l) {
        ln_kernel<<<512, 256, 0, stream>>>(x, ln1_s + l * Cv, ln1_b + l * Cv, h_bf);
        gemm_bf16<0, 128><<<dim3(36, 16), 256, 0, stream>>>(
            h_bf, w0 + (size_t)l * 2304 * Cv, attn_b + l * 2304, nullptr, nullptr,
            qkv_bf, vt_bf, Mv, 2304, Cv);
        attn_kernel<<<dim3(24, 16), 256, 0, stream>>>(qkv_bf, vt_bf, att_bf);
        gemm_bf16<1, 64><<<dim3(12, 32), 256, 0, stream>>>(
            att_bf, w1 + (size_t)l * Cv * Cv, aproj_b + l * Cv, x, x, nullptr,
            nullptr, Mv, Cv, Cv);
        ln_kernel<<<512, 256, 0, stream>>>(x, ln2_s + l * Cv, ln2_b + l * Cv, h_bf);
        gemm_bf16<2, 128><<<dim3(48, 16), 256, 0, stream>>>(
            h_bf, w2 + (size_t)l * 3072 * Cv, fc_b + l * 3072, nullptr, nullptr,
            fco_bf, nullptr, Mv, 3072, Cv);
        gemm_bf16<1, 64><<<dim3(12, 32), 256, 0, stream>>>(
            fco_bf, w3 + (size_t)l * Cv * 3072, mproj_b + l * Cv, x, x, nullptr,
            nullptr, Mv, Cv, 3072);
    }

    ln_kernel<<<512, 256, 0, stream>>>(x, lnf_s, lnf_b, h_bf);
    lmhead_kernel<<<8 * NT2, 512, 0, stream>>>(h_bf, wte_bf, out, pLse);
    plse_reduce_kernel<<<512, 256, 0, stream>>>(pLse, out, targets, lossSlot);
}

// Round 13
// 922.343 us; speedup vs baseline: 2.5898x; 2.5898x over previous
//
#include <hip/hip_runtime.h>
#include <hip/hip_bf16.h>
#include <math.h>

typedef __attribute__((ext_vector_type(8))) short bf16x8;
typedef __attribute__((ext_vector_type(4))) float f32x4;

static constexpr int Bv   = 2;
static constexpr int Tv   = 1024;
static constexpr int Cv   = 768;
static constexpr int Hv   = 12;
static constexpr int Lv   = 4;
static constexpr int Vv   = 50257;
static constexpr int Mv   = 2048;
static constexpr int NT2  = 197;          // lm-head col tiles of 256
static constexpr float EPSv = 1e-6f;

// ---------------------------------------------------------------------------
__device__ __forceinline__ void gload16(const void* g, void* l) {
    __builtin_amdgcn_global_load_lds((const __attribute__((address_space(1))) void*)g,
                                     (__attribute__((address_space(3))) void*)l, 16, 0, 0);
}
template<int N>
__device__ __forceinline__ void waitvm_barrier() {
    if constexpr (N == 0)      asm volatile("s_waitcnt vmcnt(0)\ns_barrier" ::: "memory");
    else if constexpr (N == 2) asm volatile("s_waitcnt vmcnt(2)\ns_barrier" ::: "memory");
    else if constexpr (N == 3) asm volatile("s_waitcnt vmcnt(3)\ns_barrier" ::: "memory");
    else if constexpr (N == 4) asm volatile("s_waitcnt vmcnt(4)\ns_barrier" ::: "memory");
    else if constexpr (N == 6) asm volatile("s_waitcnt vmcnt(6)\ns_barrier" ::: "memory");
    else                       asm volatile("s_waitcnt vmcnt(8)\ns_barrier" ::: "memory");
}
__device__ __forceinline__ void lgkm0_barrier() {
    asm volatile("s_waitcnt lgkmcnt(0)\ns_barrier" ::: "memory");
}

// ---------------------------------------------------------------------------
__global__ void embed_kernel(const int* __restrict__ idx,
                             const float* __restrict__ wte,
                             const float* __restrict__ wpe,
                             float* __restrict__ x) {
    int row = blockIdx.x;
    int t   = row & (Tv - 1);
    int tok = idx[row];
    const float* src = wte + (size_t)tok * Cv;
    const float* pos = wpe + (size_t)t * Cv;
    float* dst = x + (size_t)row * Cv;
    for (int c = threadIdx.x; c < Cv; c += 256)
        dst[c] = src[c] + pos[c];
}

// ---------------------------------------------------------------------------
__device__ __forceinline__ ushort4 pack4bf(float4 v) {
    ushort4 u;
    u.x = __bfloat16_as_ushort(__float2bfloat16(v.x));
    u.y = __bfloat16_as_ushort(__float2bfloat16(v.y));
    u.z = __bfloat16_as_ushort(__float2bfloat16(v.z));
    u.w = __bfloat16_as_ushort(__float2bfloat16(v.w));
    return u;
}

// LayerNorm, one wave per row. fp32 in -> bf16 out. grid 512 x 256.
__global__ void ln_kernel(const float* __restrict__ in,
                          const float* __restrict__ sc,
                          const float* __restrict__ bi,
                          __hip_bfloat16* __restrict__ out) {
    int row  = blockIdx.x * 4 + (threadIdx.x >> 6);
    int lane = threadIdx.x & 63;
    const float4* xr = (const float4*)(in + (size_t)row * Cv);
    float4 a = xr[lane], b = xr[lane + 64], c = xr[lane + 128];
    float sum = a.x + a.y + a.z + a.w + b.x + b.y + b.z + b.w + c.x + c.y + c.z + c.w;
    float sq  = a.x*a.x + a.y*a.y + a.z*a.z + a.w*a.w
              + b.x*b.x + b.y*b.y + b.z*b.z + b.w*b.w
              + c.x*c.x + c.y*c.y + c.z*c.z + c.w*c.w;
    #pragma unroll
    for (int off = 32; off; off >>= 1) {
        sum += __shfl_xor(sum, off, 64);
        sq  += __shfl_xor(sq,  off, 64);
    }
    float mean = sum * (1.0f / Cv);
    float var  = sq * (1.0f / Cv) - mean * mean;
    float rs   = rsqrtf(var + EPSv);
    const float4* s4 = (const float4*)sc;
    const float4* b4 = (const float4*)bi;
    ushort4* orow = (ushort4*)(out + (size_t)row * Cv);
    #pragma unroll
    for (int i = 0; i < 3; ++i) {
        float4 v = (i == 0) ? a : (i == 1) ? b : c;
        float4 s = s4[lane + 64 * i];
        float4 t = b4[lane + 64 * i];
        float4 o;
        o.x = (v.x - mean) * rs * s.x + t.x;
        o.y = (v.y - mean) * rs * s.y + t.y;
        o.z = (v.z - mean) * rs * s.z + t.z;
        o.w = (v.w - mean) * rs * s.w + t.w;
        orow[lane + 64 * i] = pack4bf(o);
    }
}

// ---------------------------------------------------------------------------
// ALL weight transposes + wte cvt + lossSlot zero in ONE launch.
// blocks: [0,6912) attn, [6912,9216) aproj, [9216,18432) fc,
//         [18432,27648) mproj, [27648, 32384) wte fp32->bf16 grid-stride
// ---------------------------------------------------------------------------
__global__ void wtrans_all_kernel(const float* __restrict__ a0, __hip_bfloat16* __restrict__ o0,
                                  const float* __restrict__ a1, __hip_bfloat16* __restrict__ o1,
                                  const float* __restrict__ a2, __hip_bfloat16* __restrict__ o2,
                                  const float* __restrict__ a3, __hip_bfloat16* __restrict__ o3,
                                  const float* __restrict__ wte, __hip_bfloat16* __restrict__ wte_bf,
                                  float* __restrict__ lossSlot) {
    int bid = blockIdx.x;
    if (bid >= 27648) {                    // wte convert part
        int cb = bid - 27648;
        if (cb == 0 && threadIdx.x == 0) *lossSlot = 0.f;
        int n4 = (Vv * Cv) / 4;
        int stride = 4736 * 256;
        for (int i = cb * 256 + threadIdx.x; i < n4; i += stride) {
            float4 v = ((const float4*)wte)[i];
            ((ushort4*)wte_bf)[i] = pack4bf(v);
        }
        return;
    }
    __shared__ float tile[32][33];
    const float* in; __hip_bfloat16* out; int K, N, t;
    if (bid < 6912)       { int l = bid / 1728;          t = bid % 1728;
        in = a0 + (size_t)l * 768 * 2304; out = o0 + (size_t)l * 2304 * 768; K = 768;  N = 2304; }
    else if (bid < 9216)  { int r = bid - 6912;  int l = r / 576;  t = r % 576;
        in = a1 + (size_t)l * 768 * 768;  out = o1 + (size_t)l * 768 * 768;  K = 768;  N = 768;  }
    else if (bid < 18432) { int r = bid - 9216;  int l = r / 2304; t = r % 2304;
        in = a2 + (size_t)l * 768 * 3072; out = o2 + (size_t)l * 3072 * 768; K = 768;  N = 3072; }
    else                  { int r = bid - 18432; int l = r / 2304; t = r % 2304;
        in = a3 + (size_t)l * 3072 * 768; out = o3 + (size_t)l * 768 * 3072; K = 3072; N = 768;  }
    int nx = N / 32;
    int n0 = (t % nx) * 32, k0 = (t / nx) * 32;
    int tx = threadIdx.x & 31, ty = threadIdx.x >> 5;
    #pragma unroll
    for (int i = 0; i < 4; ++i)
        tile[ty + i * 8][tx] = in[(size_t)(k0 + ty + i * 8) * N + n0 + tx];
    __syncthreads();
    #pragma unroll
    for (int i = 0; i < 4; ++i)
        out[(size_t)(n0 + ty + i * 8) * K + k0 + tx] =
            __float2bfloat16(tile[tx][ty + i * 8]);
}

// ---------------------------------------------------------------------------
// Loop GEMM, BK=64, 2-buffer 2-phase schedule (round-11 proven).
// ---------------------------------------------------------------------------
template<int EPI, int BM>
__launch_bounds__(256)
__global__ void gemm_bf16(const __hip_bfloat16* __restrict__ A,
                          const __hip_bfloat16* __restrict__ Bt,
                          const float* __restrict__ bias,
                          const float* R, float* Cf,
                          __hip_bfloat16* __restrict__ Cb,
                          __hip_bfloat16* __restrict__ vt,
                          int M, int N, int K) {
    constexpr int FM  = BM / 32;
    constexpr int NIA = BM / 32;
    constexpr int LPT = NIA + 2;
    __shared__ __hip_bfloat16 As[2][BM * 64];
    __shared__ __hip_bfloat16 Bs[2][64 * 64];
    int tid = threadIdx.x;
    int wave = tid >> 6, lane = tid & 63;
    int wr = wave >> 1, wc = wave & 1;
    int rowBase = blockIdx.y * BM, colBase = blockIdx.x * 64;

    f32x4 acc[FM][2] = {};

    int r8 = lane >> 3;
    int cg = ((lane & 7) ^ r8) * 8;
    const __hip_bfloat16* ApS = A  + (size_t)(rowBase + wave * 8 + r8) * K + cg;
    const __hip_bfloat16* BpS = Bt + (size_t)(colBase + wave * 8 + r8) * K + cg;

    auto stage = [&](int buf, int t) {
        int k0 = t * 64;
        #pragma unroll
        for (int i = 0; i < NIA; ++i)
            gload16(ApS + (size_t)(i * 32) * K + k0, &As[buf][(i * 32 + wave * 8) * 64]);
        #pragma unroll
        for (int i = 0; i < 2; ++i)
            gload16(BpS + (size_t)(i * 32) * K + k0, &Bs[buf][(i * 32 + wave * 8) * 64]);
    };

    int fq = lane >> 4, fr = lane & 15;
    int fr7 = fr & 7;

    int nt = K / 64;
    stage(0, 0); stage(1, 1);
    waitvm_barrier<LPT>();

    for (int t = 0; t < nt; ++t) {
        int cur = t & 1;
        const __hip_bfloat16* Ab = &As[cur][0];
        const __hip_bfloat16* Bb = &Bs[cur][0];

        bf16x8 av0[FM], bv0[2];
        #pragma unroll
        for (int m = 0; m < FM; ++m)
            av0[m] = *(const bf16x8*)&Ab[(wr * (BM / 2) + m * 16 + fr) * 64 + ((fq ^ fr7) * 8)];
        #pragma unroll
        for (int n = 0; n < 2; ++n)
            bv0[n] = *(const bf16x8*)&Bb[(wc * 32 + n * 16 + fr) * 64 + ((fq ^ fr7) * 8)];
        __builtin_amdgcn_s_setprio(1);
        #pragma unroll
        for (int m = 0; m < FM; ++m)
            #pragma unroll
            for (int n = 0; n < 2; ++n)
                acc[m][n] = __builtin_amdgcn_mfma_f32_16x16x32_bf16(
                    av0[m], bv0[n], acc[m][n], 0, 0, 0);
        __builtin_amdgcn_s_setprio(0);

        bf16x8 av1[FM], bv1[2];
        #pragma unroll
        for (int m = 0; m < FM; ++m)
            av1[m] = *(const bf16x8*)&Ab[(wr * (BM / 2) + m * 16 + fr) * 64 + (((4 + fq) ^ fr7) * 8)];
        #pragma unroll
        for (int n = 0; n < 2; ++n)
            bv1[n] = *(const bf16x8*)&Bb[(wc * 32 + n * 16 + fr) * 64 + (((4 + fq) ^ fr7) * 8)];
        lgkm0_barrier();

        if (t + 2 < nt) stage(cur, t + 2);

        __builtin_amdgcn_s_setprio(1);
        #pragma unroll
        for (int m = 0; m < FM; ++m)
            #pragma unroll
            for (int n = 0; n < 2; ++n)
                acc[m][n] = __builtin_amdgcn_mfma_f32_16x16x32_bf16(
                    av1[m], bv1[n], acc[m][n], 0, 0, 0);
        __builtin_amdgcn_s_setprio(0);

        if (t + 2 < nt) waitvm_barrier<LPT>();
        else            waitvm_barrier<0>();
    }

    // Fused V-transpose path (qkv GEMM only).
    if (EPI == 0 && vt != nullptr && (blockIdx.x % 3) == 2) {
        __hip_bfloat16 (*Ts)[132] = (__hip_bfloat16(*)[132])&As[0][0];
        #pragma unroll
        for (int m = 0; m < FM; ++m) {
            #pragma unroll
            for (int n = 0; n < 2; ++n) {
                int dloc = wc * 32 + n * 16 + fr;
                #pragma unroll
                for (int j = 0; j < 4; ++j) {
                    int tl = wr * (BM / 2) + m * 16 + fq * 4 + j;
                    float val = acc[m][n][j] + bias[colBase + dloc];
                    Ts[dloc][tl] = __float2bfloat16(val);
                }
            }
        }
        __syncthreads();
        int h  = blockIdx.x / 3;
        int b  = rowBase >> 10;
        int bh = b * Hv + h;
        int t0 = rowBase & 1023;
        int d = tid >> 2, part = tid & 3;
        const ushort4* src = (const ushort4*)&Ts[d][part * 32];
        ushort4* dst = (ushort4*)((__hip_bfloat16*)vt +
                       ((size_t)bh * 64 + d) * Tv + t0 + part * 32);
        #pragma unroll
        for (int i = 0; i < 8; ++i) dst[i] = src[i];
        return;
    }

    #pragma unroll
    for (int m = 0; m < FM; ++m) {
        #pragma unroll
        for (int n = 0; n < 2; ++n) {
            f32x4 v = acc[m][n];
            int col = colBase + wc * 32 + n * 16 + fr;
            #pragma unroll
            for (int j = 0; j < 4; ++j) {
                int row = rowBase + wr * (BM / 2) + m * 16 + fq * 4 + j;
                float val = v[j] + bias[col];
                if (EPI == 1) {
                    val += R[(size_t)row * N + col];
                    Cf[(size_t)row * N + col] = val;
                } else {
                    if (EPI == 2) {
                        float u = val;
                        float cc = 0.7978845608028654f * (u + 0.044715f * u * u * u);
                        val = 0.5f * u * (1.0f + tanhf(cc));
                    }
                    Cb[(size_t)row * N + col] = __float2bfloat16(val);
                }
            }
        }
    }
}

// ---------------------------------------------------------------------------
// MFMA flash attention (unchanged).
// ---------------------------------------------------------------------------
__launch_bounds__(256)
__global__ void attn_kernel(const __hip_bfloat16* __restrict__ qkv,
                            const __hip_bfloat16* __restrict__ vt,
                            __hip_bfloat16* __restrict__ att) {
    __shared__ __hip_bfloat16 Qs[64 * 64];
    __shared__ __hip_bfloat16 Ks[64 * 64];
    __shared__ __hip_bfloat16 Vs[64 * 64];   // Vs[d][k]
    __shared__ __hip_bfloat16 Ps[64 * 64];
    int bh = blockIdx.x;
    int b = bh / Hv, h = bh % Hv;
    int qt = (int)gridDim.y - 1 - (int)blockIdx.y;
    int q0 = qt * 64;
    int tid = threadIdx.x, wave = tid >> 6, lane = tid & 63;
    int g = lane >> 4, fr = lane & 15;
    int srow8 = lane >> 3, sc8 = lane & 7;

    const __hip_bfloat16* qbase = qkv + (size_t)(b * Tv + q0) * 2304 + h * 192;
    #pragma unroll
    for (int i = 0; i < 2; ++i) {
        int row = wave * 16 + i * 8 + srow8;
        gload16(qbase + (size_t)row * 2304 + ((sc8 ^ (row & 7)) * 8),
                Qs + (wave * 16 + i * 8) * 64);
    }

    f32x4 accO[4] = {};
    float mrun[4] = {-1e30f, -1e30f, -1e30f, -1e30f};
    float lrun[4] = {0.f, 0.f, 0.f, 0.f};

    for (int kv = 0; kv <= qt; ++kv) {
        int s0 = kv * 64;
        __syncthreads();
        const __hip_bfloat16* kbase = qkv + (size_t)(b * Tv + s0) * 2304 + h * 192 + 64;
        const __hip_bfloat16* vbase = vt + (size_t)bh * 64 * Tv + s0;
        #pragma unroll
        for (int i = 0; i < 2; ++i) {
            int row = wave * 16 + i * 8 + srow8;
            gload16(kbase + (size_t)row * 2304 + ((sc8 ^ (row & 7)) * 8),
                    Ks + (wave * 16 + i * 8) * 64);
            gload16(vbase + (size_t)row * Tv + ((sc8 ^ (row & 7)) * 8),
                    Vs + (wave * 16 + i * 8) * 64);
        }
        __syncthreads();

        f32x4 s4[4] = {};
        #pragma unroll
        for (int kk = 0; kk < 2; ++kk) {
            int qrow = wave * 16 + fr;
            bf16x8 qa = *(const bf16x8*)&Qs[qrow * 64 + (((g + 4 * kk) ^ (fr & 7)) * 8)];
            #pragma unroll
            for (int n = 0; n < 4; ++n) {
                int krow = n * 16 + fr;
                bf16x8 kb = *(const bf16x8*)&Ks[krow * 64 + (((g + 4 * kk) ^ (fr & 7)) * 8)];
                s4[n] = __builtin_amdgcn_mfma_f32_16x16x32_bf16(qa, kb, s4[n], 0, 0, 0);
            }
        }

        bool dia = (kv == qt);
        #pragma unroll
        for (int j = 0; j < 4; ++j) {
            int qg = q0 + wave * 16 + g * 4 + j;
            float sj[4], mx = -1e30f;
            #pragma unroll
            for (int n = 0; n < 4; ++n) {
                float v = s4[n][j] * 0.125f;
                if (dia && (s0 + n * 16 + fr) > qg) v = -1e30f;
                sj[n] = v;
                mx = fmaxf(mx, v);
            }
            #pragma unroll
            for (int off = 1; off < 16; off <<= 1)
                mx = fmaxf(mx, __shfl_xor(mx, off, 64));
            float mnew = fmaxf(mrun[j], mx);
            float ps = 0.f;
            unsigned short pb[4];
            #pragma unroll
            for (int n = 0; n < 4; ++n) {
                float p = __expf(sj[n] - mnew);
                __hip_bfloat16 pc = __float2bfloat16(p);
                pb[n] = __bfloat16_as_ushort(pc);
                ps += __bfloat162float(pc);
            }
            #pragma unroll
            for (int off = 1; off < 16; off <<= 1)
                ps += __shfl_xor(ps, off, 64);
            float cr = __expf(mrun[j] - mnew);
            lrun[j] = lrun[j] * cr + ps;
            mrun[j] = mnew;
            int prow = wave * 16 + g * 4 + j;
            #pragma unroll
            for (int n = 0; n < 4; ++n) {
                int byteoff = (32 * n + 2 * fr) ^ ((prow & 7) << 4);
                ((unsigned short*)Ps)[prow * 64 + (byteoff >> 1)] = pb[n];
            }
            #pragma unroll
            for (int n = 0; n < 4; ++n) accO[n][j] *= cr;
        }
        __syncthreads();

        #pragma unroll
        for (int kk = 0; kk < 2; ++kk) {
            int prow = wave * 16 + fr;
            bf16x8 pa = *(const bf16x8*)&Ps[prow * 64 + (((g + 4 * kk) ^ (fr & 7)) * 8)];
            #pragma unroll
            for (int n = 0; n < 4; ++n) {
                int vrow = n * 16 + fr;
                bf16x8 vb = *(const bf16x8*)&Vs[vrow * 64 + (((g + 4 * kk) ^ (fr & 7)) * 8)];
                accO[n] = __builtin_amdgcn_mfma_f32_16x16x32_bf16(pa, vb, accO[n], 0, 0, 0);
            }
        }
    }

    #pragma unroll
    for (int j = 0; j < 4; ++j) {
        float inv = 1.0f / lrun[j];
        int row = b * Tv + q0 + wave * 16 + g * 4 + j;
        #pragma unroll
        for (int n = 0; n < 4; ++n)
            att[(size_t)row * Cv + h * 64 + n * 16 + fr] =
                __float2bfloat16(accO[n][j] * inv);
    }
}

// ---------------------------------------------------------------------------
// lm-head (round-10 proven, 292 us): 256x256 tile, 8 waves, BK=64, 2-buffer
// phase-split (T2 swizzle + T4 counted vmcnt + T5 setprio), fused exp-sum.
// grid 1576 = 8 rowT x 197 colT, bijective XCD swizzle. 1 block/CU
// (acc[8][4]=128 regs pins the 256-reg slot; do NOT force min-waves — r12).
// ---------------------------------------------------------------------------
__launch_bounds__(512, 1)
__global__ void lmhead_kernel(const __hip_bfloat16* __restrict__ A,
                              const __hip_bfloat16* __restrict__ Bt,
                              float* __restrict__ Cf,
                              float* __restrict__ pLse) {
    constexpr int K = Cv, N = Vv;
    constexpr int nt = K / 64;               // 12
    __shared__ __hip_bfloat16 As[2][16384];
    __shared__ __hip_bfloat16 Bs[2][16384];
    __shared__ float ps[4][256];

    int bid = blockIdx.x;
    int nid = (bid & 7) * NT2 + (bid >> 3);
    int rowT = nid & 7, colT = nid >> 3;
    int rowBase = rowT * 256, colBase = colT * 256;

    int tid = threadIdx.x;
    int wv = tid >> 6, lane = tid & 63;
    int wr = wv >> 2, wc = wv & 3;
    int fq = lane >> 4, fr = lane & 15;
    int fr7 = fr & 7;

    f32x4 acc[8][4] = {};

    int r8 = lane >> 3;
    int cOff = ((lane & 7) ^ r8) * 8;
    const __hip_bfloat16* ApS[4];
    const __hip_bfloat16* BpS[4];
    #pragma unroll
    for (int i = 0; i < 4; ++i) {
        int rit = wv * 32 + i * 8 + r8;
        ApS[i] = A + (size_t)(rowBase + rit) * K + cOff;
        int rb = colBase + rit;
        if (rb >= N) rb = N - 1;
        BpS[i] = Bt + (size_t)rb * K + cOff;
    }

    auto stage = [&](int buf, int tile) {
        int k0 = tile * 64;
        #pragma unroll
        for (int i = 0; i < 4; ++i)
            gload16(ApS[i] + k0, &As[buf][(wv * 4 + i) * 512]);
        #pragma unroll
        for (int i = 0; i < 4; ++i)
            gload16(BpS[i] + k0, &Bs[buf][(wv * 4 + i) * 512]);
    };

    stage(0, 0);
    stage(1, 1);
    waitvm_barrier<8>();

    for (int t = 0; t < nt; ++t) {
        int cur = t & 1;
        const __hip_bfloat16* Ab = &As[cur][0];
        const __hip_bfloat16* Bb = &Bs[cur][0];

        bf16x8 av0[8], bv0[4];
        #pragma unroll
        for (int m = 0; m < 8; ++m)
            av0[m] = *(const bf16x8*)&Ab[(wr * 128 + m * 16 + fr) * 64 + ((fq ^ fr7) * 8)];
        #pragma unroll
        for (int n = 0; n < 4; ++n)
            bv0[n] = *(const bf16x8*)&Bb[(wc * 64 + n * 16 + fr) * 64 + ((fq ^ fr7) * 8)];
        __builtin_amdgcn_s_setprio(1);
        #pragma unroll
        for (int m = 0; m < 8; ++m)
            #pragma unroll
            for (int n = 0; n < 4; ++n)
                acc[m][n] = __builtin_amdgcn_mfma_f32_16x16x32_bf16(
                    av0[m], bv0[n], acc[m][n], 0, 0, 0);
        __builtin_amdgcn_s_setprio(0);

        bf16x8 av1[8], bv1[4];
        #pragma unroll
        for (int m = 0; m < 8; ++m)
            av1[m] = *(const bf16x8*)&Ab[(wr * 128 + m * 16 + fr) * 64 + (((4 + fq) ^ fr7) * 8)];
        #pragma unroll
        for (int n = 0; n < 4; ++n)
            bv1[n] = *(const bf16x8*)&Bb[(wc * 64 + n * 16 + fr) * 64 + (((4 + fq) ^ fr7) * 8)];
        lgkm0_barrier();

        if (t + 2 < nt) stage(cur, t + 2);

        __builtin_amdgcn_s_setprio(1);
        #pragma unroll
        for (int m = 0; m < 8; ++m)
            #pragma unroll
            for (int n = 0; n < 4; ++n)
                acc[m][n] = __builtin_amdgcn_mfma_f32_16x16x32_bf16(
                    av1[m], bv1[n], acc[m][n], 0, 0, 0);
        __builtin_amdgcn_s_setprio(0);

        if (t + 2 < nt) waitvm_barrier<8>();
        else            waitvm_barrier<0>();
    }

    #pragma unroll
    for (int m = 0; m < 8; ++m) {
        #pragma unroll
        for (int j = 0; j < 4; ++j) {
            int row = rowBase + wr * 128 + m * 16 + fq * 4 + j;
            float s = 0.f;
            #pragma unroll
            for (int n = 0; n < 4; ++n) {
                int col = colBase + wc * 64 + n * 16 + fr;
                float v = acc[m][n][j];
                if (col < N) {
                    Cf[(size_t)row * N + col] = v;
                    s += __expf(v);
                }
            }
            #pragma unroll
            for (int off = 1; off < 16; off <<= 1)
                s += __shfl_xor(s, off, 64);
            if (fr == 0)
                ps[wc][wr * 128 + m * 16 + fq * 4 + j] = s;
        }
    }
    __syncthreads();
    if (tid < 256)
        pLse[(size_t)(rowBase + tid) * NT2 + colT] =
            ps[0][tid] + ps[1][tid] + ps[2][tid] + ps[3][tid];
}

// ---------------------------------------------------------------------------
__global__ void plse_reduce_kernel(const float* __restrict__ pLse,
                                   const float* __restrict__ logits,
                                   const int* __restrict__ targets,
                                   float* __restrict__ lossOut) {
    int wave = threadIdx.x >> 6;
    int row  = blockIdx.x * 4 + wave;
    int lane = threadIdx.x & 63;
    const float* pr = pLse + (size_t)row * NT2;
    float l = 0.f;
    for (int i = lane; i < NT2; i += 64) l += pr[i];
    #pragma unroll
    for (int off = 32; off; off >>= 1) l += __shfl_xor(l, off, 64);
    __shared__ float sr[4];
    if (lane == 0)
        sr[wave] = logf(l) - logits[(size_t)row * Vv + targets[row]];
    __syncthreads();
    if (threadIdx.x == 0)
        atomicAdd(lossOut, (sr[0] + sr[1] + sr[2] + sr[3]) * (1.0f / Mv));
}

// ---------------------------------------------------------------------------
extern "C" void kernel_launch(void* const* d_in, const int* in_sizes, int n_in,
                              void* d_out, int out_size, void* d_ws, size_t ws_size,
                              hipStream_t stream) {
    const int*   idx     = (const int*)  d_in[0];
    const int*   targets = (const int*)  d_in[1];
    const float* wte     = (const float*)d_in[2];
    const float* wpe     = (const float*)d_in[3];
    const float* ln1_s   = (const float*)d_in[4];
    const float* ln1_b   = (const float*)d_in[5];
    const float* attn_k  = (const float*)d_in[6];
    const float* attn_b  = (const float*)d_in[7];
    const float* aproj_k = (const float*)d_in[8];
    const float* aproj_b = (const float*)d_in[9];
    const float* ln2_s   = (const float*)d_in[10];
    const float* ln2_b   = (const float*)d_in[11];
    const float* fc_k    = (const float*)d_in[12];
    const float* fc_b    = (const float*)d_in[13];
    const float* mproj_k = (const float*)d_in[14];
    const float* mproj_b = (const float*)d_in[15];
    const float* lnf_s   = (const float*)d_in[16];
    const float* lnf_b   = (const float*)d_in[17];

    float* out = (float*)d_out;
    char* ws  = (char*)d_ws;
    char* ob  = (char*)d_out;   // d_out doubles as loop-time scratch

    constexpr size_t NEED = 81962496ULL;
    if (ws_size < NEED) return;

    // ws: live through lm-head
    __hip_bfloat16* wte_bf = (__hip_bfloat16*)(ws + 0);          // 77,194,752
    __hip_bfloat16* h_bf   = (__hip_bfloat16*)(ws + 77194752);   //  3,145,728
    float*          pLse   = (float*)(ws + 80340480);            //  1,613,824

    // d_out scratch: all dead before lmhead writes logits
    float*          x      = (float*)(ob + 0);                   //  6,291,456
    __hip_bfloat16* qkv_bf = (__hip_bfloat16*)(ob + 6291456);    //  9,437,184
    __hip_bfloat16* vt_bf  = (__hip_bfloat16*)(ob + 15728640);   //  3,145,728
    __hip_bfloat16* att_bf = (__hip_bfloat16*)(ob + 18874368);   //  3,145,728
    __hip_bfloat16* fco_bf = (__hip_bfloat16*)(ob + 22020096);   // 12,582,912
    __hip_bfloat16* w0     = (__hip_bfloat16*)(ob + 34603008);   // 14,155,776 (4 layers)
    __hip_bfloat16* w1     = (__hip_bfloat16*)(ob + 48758784);   //  4,718,592
    __hip_bfloat16* w2     = (__hip_bfloat16*)(ob + 53477376);   // 18,874,368
    __hip_bfloat16* w3     = (__hip_bfloat16*)(ob + 72351744);   // 18,874,368

    float* lossSlot = out + (out_size - 1);

    embed_kernel<<<Mv, 256, 0, stream>>>(idx, wte, wpe, x);

    // all weight transposes + wte convert + lossSlot zero in one launch
    wtrans_all_kernel<<<32384, 256, 0, stream>>>(
        attn_k, w0, aproj_k, w1, fc_k, w2, mproj_k, w3, wte, wte_bf, lossSlot);

    for (int l = 0; l < Lv; ++l) {
        ln_kernel<<<512, 256, 0, stream>>>(x, ln1_s + l * Cv, ln1_b + l * Cv, h_bf);
        gemm_bf16<0, 128><<<dim3(36, 16), 256, 0, stream>>>(
            h_bf, w0 + (size_t)l * 2304 * Cv, attn_b + l * 2304, nullptr, nullptr,
            qkv_bf, vt_bf, Mv, 2304, Cv);
        attn_kernel<<<dim3(24, 16), 256, 0, stream>>>(qkv_bf, vt_bf, att_bf);
        gemm_bf16<1, 64><<<dim3(12, 32), 256, 0, stream>>>(
            att_bf, w1 + (size_t)l * Cv * Cv, aproj_b + l * Cv, x, x, nullptr,
            nullptr, Mv, Cv, Cv);
        ln_kernel<<<512, 256, 0, stream>>>(x, ln2_s + l * Cv, ln2_b + l * Cv, h_bf);
        gemm_bf16<2, 128><<<dim3(48, 16), 256, 0, stream>>>(
            h_bf, w2 + (size_t)l * 3072 * Cv, fc_b + l * 3072, nullptr, nullptr,
            fco_bf, nullptr, Mv, 3072, Cv);
        gemm_bf16<1, 64><<<dim3(12, 32), 256, 0, stream>>>(
            fco_bf, w3 + (size_t)l * Cv * 3072, mproj_b + l * Cv, x, x, nullptr,
            nullptr, Mv, Cv, 3072);
    }

    ln_kernel<<<512, 256, 0, stream>>>(x, lnf_s, lnf_b, h_bf);
    lmhead_kernel<<<8 * NT2, 512, 0, stream>>>(h_bf, wte_bf, out, pLse);
    plse_reduce_kernel<<<512, 256, 0, stream>>>(pLse, out, targets, lossSlot);
}

// Round 14
// 875.186 us; speedup vs baseline: 2.7293x; 1.0539x over previous
//
#include <hip/hip_runtime.h>
#include <hip/hip_bf16.h>
#include <math.h>

typedef __attribute__((ext_vector_type(8))) short bf16x8;
typedef __attribute__((ext_vector_type(4))) float f32x4;

static constexpr int Bv   = 2;
static constexpr int Tv   = 1024;
static constexpr int Cv   = 768;
static constexpr int Hv   = 12;
static constexpr int Lv   = 4;
static constexpr int Vv   = 50257;
static constexpr int Mv   = 2048;
static constexpr int NT2  = 197;          // lm-head col tiles of 256
static constexpr float EPSv = 1e-6f;

// ---------------------------------------------------------------------------
__device__ __forceinline__ void gload16(const void* g, void* l) {
    __builtin_amdgcn_global_load_lds((const __attribute__((address_space(1))) void*)g,
                                     (__attribute__((address_space(3))) void*)l, 16, 0, 0);
}
template<int N>
__device__ __forceinline__ void waitvm_barrier() {
    if constexpr (N == 0)      asm volatile("s_waitcnt vmcnt(0)\ns_barrier" ::: "memory");
    else if constexpr (N == 2) asm volatile("s_waitcnt vmcnt(2)\ns_barrier" ::: "memory");
    else if constexpr (N == 3) asm volatile("s_waitcnt vmcnt(3)\ns_barrier" ::: "memory");
    else if constexpr (N == 4) asm volatile("s_waitcnt vmcnt(4)\ns_barrier" ::: "memory");
    else if constexpr (N == 6) asm volatile("s_waitcnt vmcnt(6)\ns_barrier" ::: "memory");
    else                       asm volatile("s_waitcnt vmcnt(8)\ns_barrier" ::: "memory");
}
__device__ __forceinline__ void lgkm0_barrier() {
    asm volatile("s_waitcnt lgkmcnt(0)\ns_barrier" ::: "memory");
}

// ---------------------------------------------------------------------------
__global__ void embed_kernel(const int* __restrict__ idx,
                             const float* __restrict__ wte,
                             const float* __restrict__ wpe,
                             float* __restrict__ x) {
    int row = blockIdx.x;
    int t   = row & (Tv - 1);
    int tok = idx[row];
    const float* src = wte + (size_t)tok * Cv;
    const float* pos = wpe + (size_t)t * Cv;
    float* dst = x + (size_t)row * Cv;
    for (int c = threadIdx.x; c < Cv; c += 256)
        dst[c] = src[c] + pos[c];
}

// ---------------------------------------------------------------------------
__device__ __forceinline__ ushort4 pack4bf(float4 v) {
    ushort4 u;
    u.x = __bfloat16_as_ushort(__float2bfloat16(v.x));
    u.y = __bfloat16_as_ushort(__float2bfloat16(v.y));
    u.z = __bfloat16_as_ushort(__float2bfloat16(v.z));
    u.w = __bfloat16_as_ushort(__float2bfloat16(v.w));
    return u;
}

// LayerNorm, one wave per row. fp32 in -> bf16 out. grid 512 x 256.
__global__ void ln_kernel(const float* __restrict__ in,
                          const float* __restrict__ sc,
                          const float* __restrict__ bi,
                          __hip_bfloat16* __restrict__ out) {
    int row  = blockIdx.x * 4 + (threadIdx.x >> 6);
    int lane = threadIdx.x & 63;
    const float4* xr = (const float4*)(in + (size_t)row * Cv);
    float4 a = xr[lane], b = xr[lane + 64], c = xr[lane + 128];
    float sum = a.x + a.y + a.z + a.w + b.x + b.y + b.z + b.w + c.x + c.y + c.z + c.w;
    float sq  = a.x*a.x + a.y*a.y + a.z*a.z + a.w*a.w
              + b.x*b.x + b.y*b.y + b.z*b.z + b.w*b.w
              + c.x*c.x + c.y*c.y + c.z*c.z + c.w*c.w;
    #pragma unroll
    for (int off = 32; off; off >>= 1) {
        sum += __shfl_xor(sum, off, 64);
        sq  += __shfl_xor(sq,  off, 64);
    }
    float mean = sum * (1.0f / Cv);
    float var  = sq * (1.0f / Cv) - mean * mean;
    float rs   = rsqrtf(var + EPSv);
    const float4* s4 = (const float4*)sc;
    const float4* b4 = (const float4*)bi;
    ushort4* orow = (ushort4*)(out + (size_t)row * Cv);
    #pragma unroll
    for (int i = 0; i < 3; ++i) {
        float4 v = (i == 0) ? a : (i == 1) ? b : c;
        float4 s = s4[lane + 64 * i];
        float4 t = b4[lane + 64 * i];
        float4 o;
        o.x = (v.x - mean) * rs * s.x + t.x;
        o.y = (v.y - mean) * rs * s.y + t.y;
        o.z = (v.z - mean) * rs * s.z + t.z;
        o.w = (v.w - mean) * rs * s.w + t.w;
        orow[lane + 64 * i] = pack4bf(o);
    }
}

// ---------------------------------------------------------------------------
// ALL weight transposes in ONE launch. fp32 [K][N] -> bf16 [N][K], 4 layers.
// blocks: [0,6912) attn, [6912,9216) aproj, [9216,18432) fc, [18432,27648) mproj
// ---------------------------------------------------------------------------
__global__ void wtrans_all_kernel(const float* __restrict__ a0, __hip_bfloat16* __restrict__ o0,
                                  const float* __restrict__ a1, __hip_bfloat16* __restrict__ o1,
                                  const float* __restrict__ a2, __hip_bfloat16* __restrict__ o2,
                                  const float* __restrict__ a3, __hip_bfloat16* __restrict__ o3) {
    __shared__ float tile[32][33];
    int bid = blockIdx.x;
    const float* in; __hip_bfloat16* out; int K, N, t;
    if (bid < 6912)       { int l = bid / 1728;          t = bid % 1728;
        in = a0 + (size_t)l * 768 * 2304; out = o0 + (size_t)l * 2304 * 768; K = 768;  N = 2304; }
    else if (bid < 9216)  { int r = bid - 6912;  int l = r / 576;  t = r % 576;
        in = a1 + (size_t)l * 768 * 768;  out = o1 + (size_t)l * 768 * 768;  K = 768;  N = 768;  }
    else if (bid < 18432) { int r = bid - 9216;  int l = r / 2304; t = r % 2304;
        in = a2 + (size_t)l * 768 * 3072; out = o2 + (size_t)l * 3072 * 768; K = 768;  N = 3072; }
    else                  { int r = bid - 18432; int l = r / 2304; t = r % 2304;
        in = a3 + (size_t)l * 3072 * 768; out = o3 + (size_t)l * 768 * 3072; K = 3072; N = 768;  }
    int nx = N / 32;
    int n0 = (t % nx) * 32, k0 = (t / nx) * 32;
    int tx = threadIdx.x & 31, ty = threadIdx.x >> 5;
    #pragma unroll
    for (int i = 0; i < 4; ++i)
        tile[ty + i * 8][tx] = in[(size_t)(k0 + ty + i * 8) * N + n0 + tx];
    __syncthreads();
    #pragma unroll
    for (int i = 0; i < 4; ++i)
        out[(size_t)(n0 + ty + i * 8) * K + k0 + tx] =
            __float2bfloat16(tile[tx][ty + i * 8]);
}

// ---------------------------------------------------------------------------
// fp32 -> bf16 convert (wte), float4 granularity; also zeroes the loss slot.
// ---------------------------------------------------------------------------
__global__ void cvt_kernel(const float* __restrict__ in,
                           __hip_bfloat16* __restrict__ out, int n4,
                           float* __restrict__ lossSlot) {
    if (blockIdx.x == 0 && threadIdx.x == 0) *lossSlot = 0.f;
    int stride = gridDim.x * 256;
    for (int i = blockIdx.x * 256 + threadIdx.x; i < n4; i += stride) {
        float4 v = ((const float4*)in)[i];
        ((ushort4*)out)[i] = pack4bf(v);
    }
}

// ---------------------------------------------------------------------------
// Loop GEMM, BK=64, 2-buffer 2-phase schedule (lm-head structure ported):
// T2 chunk^row&7 swizzle, counted vmcnt (never 0 mid-loop), setprio on MFMA.
// BM x 64 tile, 4 waves (2x2), wave tile (BM/2) x 32.
//   EPI 0: Cb = bf16(acc + bias)  [+ fused V-transpose for V col-blocks]
//   EPI 1: Cf = acc + bias + R (in-place);  EPI 2: Cb = bf16(gelu(acc + bias))
// ---------------------------------------------------------------------------
template<int EPI, int BM>
__launch_bounds__(256)
__global__ void gemm_bf16(const __hip_bfloat16* __restrict__ A,
                          const __hip_bfloat16* __restrict__ Bt,
                          const float* __restrict__ bias,
                          const float* R, float* Cf,
                          __hip_bfloat16* __restrict__ Cb,
                          __hip_bfloat16* __restrict__ vt,
                          int M, int N, int K) {
    constexpr int FM  = BM / 32;
    constexpr int NIA = BM / 32;
    constexpr int LPT = NIA + 2;
    __shared__ __hip_bfloat16 As[2][BM * 64];
    __shared__ __hip_bfloat16 Bs[2][64 * 64];
    int tid = threadIdx.x;
    int wave = tid >> 6, lane = tid & 63;
    int wr = wave >> 1, wc = wave & 1;
    int rowBase = blockIdx.y * BM, colBase = blockIdx.x * 64;

    f32x4 acc[FM][2] = {};

    int r8 = lane >> 3;
    int cg = ((lane & 7) ^ r8) * 8;
    const __hip_bfloat16* ApS = A  + (size_t)(rowBase + wave * 8 + r8) * K + cg;
    const __hip_bfloat16* BpS = Bt + (size_t)(colBase + wave * 8 + r8) * K + cg;

    auto stage = [&](int buf, int t) {
        int k0 = t * 64;
        #pragma unroll
        for (int i = 0; i < NIA; ++i)
            gload16(ApS + (size_t)(i * 32) * K + k0, &As[buf][(i * 32 + wave * 8) * 64]);
        #pragma unroll
        for (int i = 0; i < 2; ++i)
            gload16(BpS + (size_t)(i * 32) * K + k0, &Bs[buf][(i * 32 + wave * 8) * 64]);
    };

    int fq = lane >> 4, fr = lane & 15;
    int fr7 = fr & 7;

    int nt = K / 64;
    stage(0, 0); stage(1, 1);
    waitvm_barrier<LPT>();

    for (int t = 0; t < nt; ++t) {
        int cur = t & 1;
        const __hip_bfloat16* Ab = &As[cur][0];
        const __hip_bfloat16* Bb = &Bs[cur][0];

        bf16x8 av0[FM], bv0[2];
        #pragma unroll
        for (int m = 0; m < FM; ++m)
            av0[m] = *(const bf16x8*)&Ab[(wr * (BM / 2) + m * 16 + fr) * 64 + ((fq ^ fr7) * 8)];
        #pragma unroll
        for (int n = 0; n < 2; ++n)
            bv0[n] = *(const bf16x8*)&Bb[(wc * 32 + n * 16 + fr) * 64 + ((fq ^ fr7) * 8)];
        __builtin_amdgcn_s_setprio(1);
        #pragma unroll
        for (int m = 0; m < FM; ++m)
            #pragma unroll
            for (int n = 0; n < 2; ++n)
                acc[m][n] = __builtin_amdgcn_mfma_f32_16x16x32_bf16(
                    av0[m], bv0[n], acc[m][n], 0, 0, 0);
        __builtin_amdgcn_s_setprio(0);

        bf16x8 av1[FM], bv1[2];
        #pragma unroll
        for (int m = 0; m < FM; ++m)
            av1[m] = *(const bf16x8*)&Ab[(wr * (BM / 2) + m * 16 + fr) * 64 + (((4 + fq) ^ fr7) * 8)];
        #pragma unroll
        for (int n = 0; n < 2; ++n)
            bv1[n] = *(const bf16x8*)&Bb[(wc * 32 + n * 16 + fr) * 64 + (((4 + fq) ^ fr7) * 8)];
        lgkm0_barrier();

        if (t + 2 < nt) stage(cur, t + 2);

        __builtin_amdgcn_s_setprio(1);
        #pragma unroll
        for (int m = 0; m < FM; ++m)
            #pragma unroll
            for (int n = 0; n < 2; ++n)
                acc[m][n] = __builtin_amdgcn_mfma_f32_16x16x32_bf16(
                    av1[m], bv1[n], acc[m][n], 0, 0, 0);
        __builtin_amdgcn_s_setprio(0);

        if (t + 2 < nt) waitvm_barrier<LPT>();
        else            waitvm_barrier<0>();
    }

    // Fused V-transpose path (qkv GEMM only).
    if (EPI == 0 && vt != nullptr && (blockIdx.x % 3) == 2) {
        __hip_bfloat16 (*Ts)[132] = (__hip_bfloat16(*)[132])&As[0][0];
        #pragma unroll
        for (int m = 0; m < FM; ++m) {
            #pragma unroll
            for (int n = 0; n < 2; ++n) {
                int dloc = wc * 32 + n * 16 + fr;
                #pragma unroll
                for (int j = 0; j < 4; ++j) {
                    int tl = wr * (BM / 2) + m * 16 + fq * 4 + j;
                    float val = acc[m][n][j] + bias[colBase + dloc];
                    Ts[dloc][tl] = __float2bfloat16(val);
                }
            }
        }
        __syncthreads();
        int h  = blockIdx.x / 3;
        int b  = rowBase >> 10;
        int bh = b * Hv + h;
        int t0 = rowBase & 1023;
        int d = tid >> 2, part = tid & 3;
        const ushort4* src = (const ushort4*)&Ts[d][part * 32];
        ushort4* dst = (ushort4*)((__hip_bfloat16*)vt +
                       ((size_t)bh * 64 + d) * Tv + t0 + part * 32);
        #pragma unroll
        for (int i = 0; i < 8; ++i) dst[i] = src[i];
        return;
    }

    #pragma unroll
    for (int m = 0; m < FM; ++m) {
        #pragma unroll
        for (int n = 0; n < 2; ++n) {
            f32x4 v = acc[m][n];
            int col = colBase + wc * 32 + n * 16 + fr;
            #pragma unroll
            for (int j = 0; j < 4; ++j) {
                int row = rowBase + wr * (BM / 2) + m * 16 + fq * 4 + j;
                float val = v[j] + bias[col];
                if (EPI == 1) {
                    val += R[(size_t)row * N + col];
                    Cf[(size_t)row * N + col] = val;
                } else {
                    if (EPI == 2) {
                        float u = val;
                        float cc = 0.7978845608028654f * (u + 0.044715f * u * u * u);
                        val = 0.5f * u * (1.0f + tanhf(cc));
                    }
                    Cb[(size_t)row * N + col] = __float2bfloat16(val);
                }
            }
        }
    }
}

// ---------------------------------------------------------------------------
// MFMA flash attention (unchanged).
// ---------------------------------------------------------------------------
__launch_bounds__(256)
__global__ void attn_kernel(const __hip_bfloat16* __restrict__ qkv,
                            const __hip_bfloat16* __restrict__ vt,
                            __hip_bfloat16* __restrict__ att) {
    __shared__ __hip_bfloat16 Qs[64 * 64];
    __shared__ __hip_bfloat16 Ks[64 * 64];
    __shared__ __hip_bfloat16 Vs[64 * 64];   // Vs[d][k]
    __shared__ __hip_bfloat16 Ps[64 * 64];
    int bh = blockIdx.x;
    int b = bh / Hv, h = bh % Hv;
    int qt = (int)gridDim.y - 1 - (int)blockIdx.y;
    int q0 = qt * 64;
    int tid = threadIdx.x, wave = tid >> 6, lane = tid & 63;
    int g = lane >> 4, fr = lane & 15;
    int srow8 = lane >> 3, sc8 = lane & 7;

    const __hip_bfloat16* qbase = qkv + (size_t)(b * Tv + q0) * 2304 + h * 192;
    #pragma unroll
    for (int i = 0; i < 2; ++i) {
        int row = wave * 16 + i * 8 + srow8;
        gload16(qbase + (size_t)row * 2304 + ((sc8 ^ (row & 7)) * 8),
                Qs + (wave * 16 + i * 8) * 64);
    }

    f32x4 accO[4] = {};
    float mrun[4] = {-1e30f, -1e30f, -1e30f, -1e30f};
    float lrun[4] = {0.f, 0.f, 0.f, 0.f};

    for (int kv = 0; kv <= qt; ++kv) {
        int s0 = kv * 64;
        __syncthreads();
        const __hip_bfloat16* kbase = qkv + (size_t)(b * Tv + s0) * 2304 + h * 192 + 64;
        const __hip_bfloat16* vbase = vt + (size_t)bh * 64 * Tv + s0;
        #pragma unroll
        for (int i = 0; i < 2; ++i) {
            int row = wave * 16 + i * 8 + srow8;
            gload16(kbase + (size_t)row * 2304 + ((sc8 ^ (row & 7)) * 8),
                    Ks + (wave * 16 + i * 8) * 64);
            gload16(vbase + (size_t)row * Tv + ((sc8 ^ (row & 7)) * 8),
                    Vs + (wave * 16 + i * 8) * 64);
        }
        __syncthreads();

        f32x4 s4[4] = {};
        #pragma unroll
        for (int kk = 0; kk < 2; ++kk) {
            int qrow = wave * 16 + fr;
            bf16x8 qa = *(const bf16x8*)&Qs[qrow * 64 + (((g + 4 * kk) ^ (fr & 7)) * 8)];
            #pragma unroll
            for (int n = 0; n < 4; ++n) {
                int krow = n * 16 + fr;
                bf16x8 kb = *(const bf16x8*)&Ks[krow * 64 + (((g + 4 * kk) ^ (fr & 7)) * 8)];
                s4[n] = __builtin_amdgcn_mfma_f32_16x16x32_bf16(qa, kb, s4[n], 0, 0, 0);
            }
        }

        bool dia = (kv == qt);
        #pragma unroll
        for (int j = 0; j < 4; ++j) {
            int qg = q0 + wave * 16 + g * 4 + j;
            float sj[4], mx = -1e30f;
            #pragma unroll
            for (int n = 0; n < 4; ++n) {
                float v = s4[n][j] * 0.125f;
                if (dia && (s0 + n * 16 + fr) > qg) v = -1e30f;
                sj[n] = v;
                mx = fmaxf(mx, v);
            }
            #pragma unroll
            for (int off = 1; off < 16; off <<= 1)
                mx = fmaxf(mx, __shfl_xor(mx, off, 64));
            float mnew = fmaxf(mrun[j], mx);
            float ps = 0.f;
            unsigned short pb[4];
            #pragma unroll
            for (int n = 0; n < 4; ++n) {
                float p = __expf(sj[n] - mnew);
                __hip_bfloat16 pc = __float2bfloat16(p);
                pb[n] = __bfloat16_as_ushort(pc);
                ps += __bfloat162float(pc);
            }
            #pragma unroll
            for (int off = 1; off < 16; off <<= 1)
                ps += __shfl_xor(ps, off, 64);
            float cr = __expf(mrun[j] - mnew);
            lrun[j] = lrun[j] * cr + ps;
            mrun[j] = mnew;
            int prow = wave * 16 + g * 4 + j;
            #pragma unroll
            for (int n = 0; n < 4; ++n) {
                int byteoff = (32 * n + 2 * fr) ^ ((prow & 7) << 4);
                ((unsigned short*)Ps)[prow * 64 + (byteoff >> 1)] = pb[n];
            }
            #pragma unroll
            for (int n = 0; n < 4; ++n) accO[n][j] *= cr;
        }
        __syncthreads();

        #pragma unroll
        for (int kk = 0; kk < 2; ++kk) {
            int prow = wave * 16 + fr;
            bf16x8 pa = *(const bf16x8*)&Ps[prow * 64 + (((g + 4 * kk) ^ (fr & 7)) * 8)];
            #pragma unroll
            for (int n = 0; n < 4; ++n) {
                int vrow = n * 16 + fr;
                bf16x8 vb = *(const bf16x8*)&Vs[vrow * 64 + (((g + 4 * kk) ^ (fr & 7)) * 8)];
                accO[n] = __builtin_amdgcn_mfma_f32_16x16x32_bf16(pa, vb, accO[n], 0, 0, 0);
            }
        }
    }

    #pragma unroll
    for (int j = 0; j < 4; ++j) {
        float inv = 1.0f / lrun[j];
        int row = b * Tv + q0 + wave * 16 + g * 4 + j;
        #pragma unroll
        for (int n = 0; n < 4; ++n)
            att[(size_t)row * Cv + h * 64 + n * 16 + fr] =
                __float2bfloat16(accO[n][j] * inv);
    }
}

// ---------------------------------------------------------------------------
// lm-head (round-8/10 proven): 256x256 tile, 8 waves, BK=64, 2-buffer
// phase-split (T2 swizzle + T4 counted vmcnt + T5 setprio), fused exp-sum.
// grid 1576 = 8 rowT x 197 colT, bijective XCD swizzle. 1 block/CU.
// ---------------------------------------------------------------------------
__launch_bounds__(512, 1)
__global__ void lmhead_kernel(const __hip_bfloat16* __restrict__ A,
                              const __hip_bfloat16* __restrict__ Bt,
                              float* __restrict__ Cf,
                              float* __restrict__ pLse) {
    constexpr int K = Cv, N = Vv;
    constexpr int nt = K / 64;               // 12
    __shared__ __hip_bfloat16 As[2][16384];
    __shared__ __hip_bfloat16 Bs[2][16384];
    __shared__ float ps[4][256];

    int bid = blockIdx.x;
    int nid = (bid & 7) * NT2 + (bid >> 3);
    int rowT = nid & 7, colT = nid >> 3;
    int rowBase = rowT * 256, colBase = colT * 256;

    int tid = threadIdx.x;
    int wv = tid >> 6, lane = tid & 63;
    int wr = wv >> 2, wc = wv & 3;
    int fq = lane >> 4, fr = lane & 15;
    int fr7 = fr & 7;

    f32x4 acc[8][4] = {};

    int r8 = lane >> 3;
    int cOff = ((lane & 7) ^ r8) * 8;
    const __hip_bfloat16* ApS[4];
    const __hip_bfloat16* BpS[4];
    #pragma unroll
    for (int i = 0; i < 4; ++i) {
        int rit = wv * 32 + i * 8 + r8;
        ApS[i] = A + (size_t)(rowBase + rit) * K + cOff;
        int rb = colBase + rit;
        if (rb >= N) rb = N - 1;
        BpS[i] = Bt + (size_t)rb * K + cOff;
    }

    auto stage = [&](int buf, int tile) {
        int k0 = tile * 64;
        #pragma unroll
        for (int i = 0; i < 4; ++i)
            gload16(ApS[i] + k0, &As[buf][(wv * 4 + i) * 512]);
        #pragma unroll
        for (int i = 0; i < 4; ++i)
            gload16(BpS[i] + k0, &Bs[buf][(wv * 4 + i) * 512]);
    };

    stage(0, 0);
    stage(1, 1);
    waitvm_barrier<8>();

    for (int t = 0; t < nt; ++t) {
        int cur = t & 1;
        const __hip_bfloat16* Ab = &As[cur][0];
        const __hip_bfloat16* Bb = &Bs[cur][0];

        bf16x8 av0[8], bv0[4];
        #pragma unroll
        for (int m = 0; m < 8; ++m)
            av0[m] = *(const bf16x8*)&Ab[(wr * 128 + m * 16 + fr) * 64 + ((fq ^ fr7) * 8)];
        #pragma unroll
        for (int n = 0; n < 4; ++n)
            bv0[n] = *(const bf16x8*)&Bb[(wc * 64 + n * 16 + fr) * 64 + ((fq ^ fr7) * 8)];
        __builtin_amdgcn_s_setprio(1);
        #pragma unroll
        for (int m = 0; m < 8; ++m)
            #pragma unroll
            for (int n = 0; n < 4; ++n)
                acc[m][n] = __builtin_amdgcn_mfma_f32_16x16x32_bf16(
                    av0[m], bv0[n], acc[m][n], 0, 0, 0);
        __builtin_amdgcn_s_setprio(0);

        bf16x8 av1[8], bv1[4];
        #pragma unroll
        for (int m = 0; m < 8; ++m)
            av1[m] = *(const bf16x8*)&Ab[(wr * 128 + m * 16 + fr) * 64 + (((4 + fq) ^ fr7) * 8)];
        #pragma unroll
        for (int n = 0; n < 4; ++n)
            bv1[n] = *(const bf16x8*)&Bb[(wc * 64 + n * 16 + fr) * 64 + (((4 + fq) ^ fr7) * 8)];
        lgkm0_barrier();

        if (t + 2 < nt) stage(cur, t + 2);

        __builtin_amdgcn_s_setprio(1);
        #pragma unroll
        for (int m = 0; m < 8; ++m)
            #pragma unroll
            for (int n = 0; n < 4; ++n)
                acc[m][n] = __builtin_amdgcn_mfma_f32_16x16x32_bf16(
                    av1[m], bv1[n], acc[m][n], 0, 0, 0);
        __builtin_amdgcn_s_setprio(0);

        if (t + 2 < nt) waitvm_barrier<8>();
        else            waitvm_barrier<0>();
    }

    #pragma unroll
    for (int m = 0; m < 8; ++m) {
        #pragma unroll
        for (int j = 0; j < 4; ++j) {
            int row = rowBase + wr * 128 + m * 16 + fq * 4 + j;
            float s = 0.f;
            #pragma unroll
            for (int n = 0; n < 4; ++n) {
                int col = colBase + wc * 64 + n * 16 + fr;
                float v = acc[m][n][j];
                if (col < N) {
                    Cf[(size_t)row * N + col] = v;
                    s += __expf(v);
                }
            }
            #pragma unroll
            for (int off = 1; off < 16; off <<= 1)
                s += __shfl_xor(s, off, 64);
            if (fr == 0)
                ps[wc][wr * 128 + m * 16 + fq * 4 + j] = s;
        }
    }
    __syncthreads();
    if (tid < 256)
        pLse[(size_t)(rowBase + tid) * NT2 + colT] =
            ps[0][tid] + ps[1][tid] + ps[2][tid] + ps[3][tid];
}

// ---------------------------------------------------------------------------
// Reduce partial sums per row -> loss contribution; atomicAdd the mean.
// ---------------------------------------------------------------------------
__global__ void plse_reduce_kernel(const float* __restrict__ pLse,
                                   const float* __restrict__ logits,
                                   const int* __restrict__ targets,
                                   float* __restrict__ lossOut) {
    int wave = threadIdx.x >> 6;
    int row  = blockIdx.x * 4 + wave;
    int lane = threadIdx.x & 63;
    const float* pr = pLse + (size_t)row * NT2;
    float l = 0.f;
    for (int i = lane; i < NT2; i += 64) l += pr[i];
    #pragma unroll
    for (int off = 32; off; off >>= 1) l += __shfl_xor(l, off, 64);
    __shared__ float sr[4];
    if (lane == 0)
        sr[wave] = logf(l) - logits[(size_t)row * Vv + targets[row]];
    __syncthreads();
    if (threadIdx.x == 0)
        atomicAdd(lossOut, (sr[0] + sr[1] + sr[2] + sr[3]) * (1.0f / Mv));
}

// ---------------------------------------------------------------------------
extern "C" void kernel_launch(void* const* d_in, const int* in_sizes, int n_in,
                              void* d_out, int out_size, void* d_ws, size_t ws_size,
                              hipStream_t stream) {
    const int*   idx     = (const int*)  d_in[0];
    const int*   targets = (const int*)  d_in[1];
    const float* wte     = (const float*)d_in[2];
    const float* wpe     = (const float*)d_in[3];
    const float* ln1_s   = (const float*)d_in[4];
    const float* ln1_b   = (const float*)d_in[5];
    const float* attn_k  = (const float*)d_in[6];
    const float* attn_b  = (const float*)d_in[7];
    const float* aproj_k = (const float*)d_in[8];
    const float* aproj_b = (const float*)d_in[9];
    const float* ln2_s   = (const float*)d_in[10];
    const float* ln2_b   = (const float*)d_in[11];
    const float* fc_k    = (const float*)d_in[12];
    const float* fc_b    = (const float*)d_in[13];
    const float* mproj_k = (const float*)d_in[14];
    const float* mproj_b = (const float*)d_in[15];
    const float* lnf_s   = (const float*)d_in[16];
    const float* lnf_b   = (const float*)d_in[17];

    float* out = (float*)d_out;
    char* ws  = (char*)d_ws;
    char* ob  = (char*)d_out;   // d_out doubles as loop-time scratch

    constexpr size_t NEED = 81962496ULL;
    if (ws_size < NEED) return;

    // ws: live through lm-head
    __hip_bfloat16* wte_bf = (__hip_bfloat16*)(ws + 0);          // 77,194,752
    __hip_bfloat16* h_bf   = (__hip_bfloat16*)(ws + 77194752);   //  3,145,728
    float*          pLse   = (float*)(ws + 80340480);            //  1,613,824

    // d_out scratch: all dead before lmhead writes logits
    float*          x      = (float*)(ob + 0);                   //  6,291,456
    __hip_bfloat16* qkv_bf = (__hip_bfloat16*)(ob + 6291456);    //  9,437,184
    __hip_bfloat16* vt_bf  = (__hip_bfloat16*)(ob + 15728640);   //  3,145,728
    __hip_bfloat16* att_bf = (__hip_bfloat16*)(ob + 18874368);   //  3,145,728
    __hip_bfloat16* fco_bf = (__hip_bfloat16*)(ob + 22020096);   // 12,582,912
    __hip_bfloat16* w0     = (__hip_bfloat16*)(ob + 34603008);   // 14,155,776 (4 layers)
    __hip_bfloat16* w1     = (__hip_bfloat16*)(ob + 48758784);   //  4,718,592
    __hip_bfloat16* w2     = (__hip_bfloat16*)(ob + 53477376);   // 18,874,368
    __hip_bfloat16* w3     = (__hip_bfloat16*)(ob + 72351744);   // 18,874,368

    float* lossSlot = out + (out_size - 1);

    embed_kernel<<<Mv, 256, 0, stream>>>(idx, wte, wpe, x);

    wtrans_all_kernel<<<27648, 256, 0, stream>>>(
        attn_k, w0, aproj_k, w1, fc_k, w2, mproj_k, w3);

    for (int l = 0; l < Lv; ++l) {
        ln_kernel<<<512, 256, 0, stream>>>(x, ln1_s + l * Cv, ln1_b + l * Cv, h_bf);
        gemm_bf16<0, 128><<<dim3(36, 16), 256, 0, stream>>>(
            h_bf, w0 + (size_t)l * 2304 * Cv, attn_b + l * 2304, nullptr, nullptr,
            qkv_bf, vt_bf, Mv, 2304, Cv);
        attn_kernel<<<dim3(24, 16), 256, 0, stream>>>(qkv_bf, vt_bf, att_bf);
        gemm_bf16<1, 64><<<dim3(12, 32), 256, 0, stream>>>(
            att_bf, w1 + (size_t)l * Cv * Cv, aproj_b + l * Cv, x, x, nullptr,
            nullptr, Mv, Cv, Cv);
        ln_kernel<<<512, 256, 0, stream>>>(x, ln2_s + l * Cv, ln2_b + l * Cv, h_bf);
        gemm_bf16<2, 128><<<dim3(48, 16), 256, 0, stream>>>(
            h_bf, w2 + (size_t)l * 3072 * Cv, fc_b + l * 3072, nullptr, nullptr,
            fco_bf, nullptr, Mv, 3072, Cv);
        gemm_bf16<1, 64><<<dim3(12, 32), 256, 0, stream>>>(
            fco_bf, w3 + (size_t)l * Cv * 3072, mproj_b + l * Cv, x, x, nullptr,
            nullptr, Mv, Cv, 3072);
    }

    ln_kernel<<<512, 256, 0, stream>>>(x, lnf_s, lnf_b, h_bf);
    cvt_kernel<<<2048, 256, 0, stream>>>(wte, wte_bf, (Vv * Cv) / 4, lossSlot);
    lmhead_kernel<<<8 * NT2, 512, 0, stream>>>(h_bf, wte_bf, out, pLse);
    plse_reduce_kernel<<<512, 256, 0, stream>>>(pLse, out, targets, lossSlot);
}